// Round 2
// baseline (844.956 us; speedup 1.0000x reference)
//
#include <hip/hip_runtime.h>
#include <hip/hip_bf16.h>

#define HOP 32
#define NB 8
#define NDIM 512
#define KDIM 32768
#define LDIM 64
#define TOUT ((KDIM - 1) * HOP + LDIM)   // 1048608
#define QTILE 64                          // q-groups (output frames) per block
#define CT_ROWS 72                        // staged c columns: [q0-8, q0+64)
#define CT_STRIDE 520                     // padded row stride in shorts (1040B, 16B-aligned)

typedef __bf16 bf16x8 __attribute__((ext_vector_type(8)));
typedef float floatx4 __attribute__((ext_vector_type(4)));

__device__ __forceinline__ unsigned short f2bf(float f) {
    unsigned int u = __float_as_uint(f);
    u += 0x7FFFu + ((u >> 16) & 1u);      // round-to-nearest-even
    return (unsigned short)(u >> 16);
}

// ---- pre-pass: V fp32 [64][512] -> bf16 bits in d_ws ----
__global__ void convert_v_kernel(const float* __restrict__ vf,
                                 unsigned short* __restrict__ vb) {
    int i = (blockIdx.x * 256 + threadIdx.x) * 4;   // 32 blocks x 256 thr x 4
    float4 v = *reinterpret_cast<const float4*>(vf + i);
    ushort4 o;
    o.x = f2bf(v.x); o.y = f2bf(v.y); o.z = f2bf(v.z); o.w = f2bf(v.w);
    *reinterpret_cast<ushort4*>(vb + i) = o;
}

__global__ __launch_bounds__(256, 2) void decoder_kernel(
        const float* __restrict__ cg,            // c fp32 [B][N][K]
        const unsigned short* __restrict__ vb,   // V bf16 bits [L][N] (from ws)
        float* __restrict__ outg)                // [B][TOUT] fp32
{
    __shared__ __align__(16) unsigned short ct[CT_ROWS * CT_STRIDE];

    const int tid  = threadIdx.x;
    const int tile = blockIdx.x;
    const int b    = blockIdx.y;
    const int q0   = tile * QTILE;
    const int lane = tid & 63;

    const long cbase = (long)b * NDIM * KDIM;

    // ---- phase A: main 64 columns c[b][n][q0 .. q0+64) -> ct rows 8..71 ----
    const bool fastA = (q0 + QTILE <= KDIM);
    #pragma unroll 4
    for (int it = 0; it < 32; ++it) {
        int id = it * 256 + tid;          // 0..8191 = 512 rows * 16 chunks
        int n  = id >> 4;
        int cc = id & 15;                 // chunk of 4 fp32 cols
        int colbase = q0 + cc * 4;
        float4 v;
        if (fastA) {
            v = *reinterpret_cast<const float4*>(cg + cbase + (long)n * KDIM + colbase);
        } else {
            float* ve = reinterpret_cast<float*>(&v);
            #pragma unroll
            for (int e = 0; e < 4; ++e) {
                int col = colbase + e;
                ve[e] = (col < KDIM) ? cg[cbase + (long)n * KDIM + col] : 0.f;
            }
        }
        unsigned short s[4];
        s[0] = f2bf(v.x); s[1] = f2bf(v.y); s[2] = f2bf(v.z); s[3] = f2bf(v.w);
        #pragma unroll
        for (int i = 0; i < 4; ++i) {
            int e = (lane + i) & 3;       // rotate to spread LDS banks
            ct[(8 + cc * 4 + e) * CT_STRIDE + n] = s[e];
        }
    }
    // ---- phase B: halo 8 columns c[b][n][q0-8 .. q0) -> ct rows 0..7 ----
    const bool fastB = (q0 >= 8);
    #pragma unroll
    for (int it = 0; it < 4; ++it) {
        int id = it * 256 + tid;          // 0..1023 = 512 rows * 2 chunks
        int n  = id >> 1;
        int cc = id & 1;
        int colbase = q0 - 8 + cc * 4;
        float4 v;
        if (fastB) {
            v = *reinterpret_cast<const float4*>(cg + cbase + (long)n * KDIM + colbase);
        } else {
            float* ve = reinterpret_cast<float*>(&v);
            #pragma unroll
            for (int e = 0; e < 4; ++e) {
                int col = colbase + e;
                ve[e] = (col >= 0) ? cg[cbase + (long)n * KDIM + col] : 0.f;
            }
        }
        unsigned short s[4];
        s[0] = f2bf(v.x); s[1] = f2bf(v.y); s[2] = f2bf(v.z); s[3] = f2bf(v.w);
        #pragma unroll
        for (int i = 0; i < 4; ++i) {
            int e = (lane + i) & 3;
            ct[(cc * 4 + e) * CT_STRIDE + n] = s[e];
        }
    }
    __syncthreads();

    // ---- MFMA main loop: out[32 x 64] = W[32 x 1024] * z[1024 x 64] ----
    // W[r, k'] = V[r + (k'<512 ? 0 : 32)][k' & 511]
    // z[k', q] = c[b][k'&511][k'<512 ? q : q-1]
    const int w   = tid >> 6;             // wave id = column tile (0..3)
    const int l15 = lane & 15;
    const int g   = lane >> 4;

    floatx4 acc0 = {0.f, 0.f, 0.f, 0.f};
    floatx4 acc1 = {0.f, 0.f, 0.f, 0.f};

    const int jlo = w * 16 + l15;         // this lane's output column (local q)

    #pragma unroll 4
    for (int ks = 0; ks < 32; ++ks) {
        const int hi   = (ks >= 16);
        const int ncol = (ks & 15) * 32 + g * 8;
        // B fragment: lane holds z[k_local = g*8+j][q = q0 + jlo]
        const unsigned short* bp = &ct[(jlo + (hi ? 7 : 8)) * CT_STRIDE + ncol];
        bf16x8 bfrag = *reinterpret_cast<const bf16x8*>(bp);
        // A fragments: lane holds W[m = l15 (+16)][k_local = g*8+j], from bf16 ws (L2-hot)
        const int vrow0 = l15 + (hi ? 32 : 0);
        bf16x8 a0 = *reinterpret_cast<const bf16x8*>(vb + vrow0 * NDIM + ncol);
        bf16x8 a1 = *reinterpret_cast<const bf16x8*>(vb + (vrow0 + 16) * NDIM + ncol);
        acc0 = __builtin_amdgcn_mfma_f32_16x16x32_bf16(a0, bfrag, acc0, 0, 0, 0);
        acc1 = __builtin_amdgcn_mfma_f32_16x16x32_bf16(a1, bfrag, acc1, 0, 0, 0);
    }

    // ---- epilogue: D col(lane&15)=q-local, row((lane>>4)*4+reg)=r ----
    const int q = q0 + w * 16 + l15;
    if (q <= KDIM) {
        long tb = (long)b * TOUT + (long)q * HOP + g * 4;
        *reinterpret_cast<floatx4*>(outg + tb)      = acc0;   // r = g*4 .. g*4+3
        *reinterpret_cast<floatx4*>(outg + tb + 16) = acc1;   // r = 16+g*4 ..
    }
}

extern "C" void kernel_launch(void* const* d_in, const int* in_sizes, int n_in,
                              void* d_out, int out_size, void* d_ws, size_t ws_size,
                              hipStream_t stream) {
    const float* c  = (const float*)d_in[0];
    const float* V  = (const float*)d_in[1];
    float* out      = (float*)d_out;
    unsigned short* vb = (unsigned short*)d_ws;   // 64*512 bf16 = 64 KB

    convert_v_kernel<<<dim3(32), dim3(256), 0, stream>>>(V, vb);
    dim3 grid(KDIM / QTILE + 1, NB);   // (513, 8)
    decoder_kernel<<<grid, dim3(256, 1, 1), 0, stream>>>(c, vb, out);
}